// Round 6
// baseline (431.203 us; speedup 1.0000x reference)
//
#include <hip/hip_runtime.h>
#include <hip/hip_bf16.h>

// MoE top-2 of 8: B=1024 tokens, M=10000, H=512.
// R6: register-staged f32 loads + counted-vmcnt pipeline (depth 2, sets P/Q),
// raw s_barrier with lgkm-only drain (vmem stays in flight across barriers).
// No global atomics; GEMM2 = two ordered passes; GEMM1 = split-K + reduce.

#define B_TOK 1024
#define M_DIM 10000
#define E_NUM 8
#define H_DIM 512
#define NSTEP 313  // ceil(10000/32)

typedef __attribute__((ext_vector_type(4))) float fx4;
typedef __attribute__((ext_vector_type(8))) short sx8;
typedef __attribute__((ext_vector_type(4))) short sx4;

#define LSTR 40           // LDS row stride in shorts: 32 data + 8 pad (2-way max)
#define BUFS (256 * LSTR) // one dbuf half: 128 A rows + 128 B rows

__device__ __forceinline__ short f2bf(float f) {
  union { __hip_bfloat16 h; short s; } u;
  u.h = __float2bfloat16(f);
  return u.s;
}

__device__ __forceinline__ sx8 pack8(fx4 a, fx4 b) {
  sx8 r;
  r[0] = f2bf(a[0]); r[1] = f2bf(a[1]); r[2] = f2bf(a[2]); r[3] = f2bf(a[3]);
  r[4] = f2bf(b[0]); r[5] = f2bf(b[1]); r[6] = f2bf(b[2]); r[7] = f2bf(b[3]);
  return r;
}

// Barrier that drains ONLY LDS ops; vmem loads stay in flight across it.
__device__ __forceinline__ void pipe_barrier() {
  asm volatile("s_waitcnt lgkmcnt(0)" ::: "memory");
  __builtin_amdgcn_sched_barrier(0);
  __builtin_amdgcn_s_barrier();
  __builtin_amdgcn_sched_barrier(0);
}

__global__ void k_zero(int* cnt, int* cnt2) {
  if (threadIdx.x < E_NUM) cnt[threadIdx.x] = 0;
  if (threadIdx.x < 2 * E_NUM) cnt2[threadIdx.x] = 0;
}

// Router: f64-accumulated logits (top-2 flip safety vs numpy ref), softmax.
__global__ __launch_bounds__(256) void k_router(
    const float* __restrict__ x, const float* __restrict__ Wr,
    int* __restrict__ cnt, int* __restrict__ cnt2,
    int* __restrict__ tokAll, int* __restrict__ qlist2, float* __restrict__ wlist2)
{
  int b = blockIdx.x, t = threadIdx.x;
  const float* xr = x + (size_t)b * M_DIM;
  double acc[E_NUM];
#pragma unroll
  for (int e = 0; e < E_NUM; e++) acc[e] = 0.0;
  for (int m = t; m < M_DIM; m += 256) {
    float xv = xr[m];
#pragma unroll
    for (int e = 0; e < E_NUM; e++)
      acc[e] += (double)xv * (double)Wr[e * M_DIM + m];
  }
#pragma unroll
  for (int e = 0; e < E_NUM; e++) {
#pragma unroll
    for (int off = 32; off > 0; off >>= 1)
      acc[e] += __shfl_xor(acc[e], off);
  }
  __shared__ double part[4][E_NUM];
  int wave = t >> 6;
  if ((t & 63) == 0) {
    for (int e = 0; e < E_NUM; e++) part[wave][e] = acc[e];
  }
  __syncthreads();
  if (t == 0) {
    double lg[E_NUM];
    for (int e = 0; e < E_NUM; e++)
      lg[e] = part[0][e] + part[1][e] + part[2][e] + part[3][e];
    int i0 = 0;
    for (int e = 1; e < E_NUM; e++) if (lg[e] > lg[i0]) i0 = e;
    int i1 = (i0 == 0) ? 1 : 0;
    for (int e = 0; e < E_NUM; e++) if (e != i0 && lg[e] > lg[i1]) i1 = e;
    double ex = exp(lg[i1] - lg[i0]);
    float p0 = (float)(1.0 / (1.0 + ex));
    float p1 = (float)(ex / (1.0 + ex));
    int q0 = atomicAdd(&cnt[i0], 1);
    tokAll[i0 * B_TOK + q0] = b;
    int j0 = atomicAdd(&cnt2[i0 * 2 + 0], 1);
    qlist2[(i0 * 2 + 0) * B_TOK + j0] = q0;
    wlist2[(i0 * 2 + 0) * B_TOK + j0] = p0;
    int q1 = atomicAdd(&cnt[i1], 1);
    tokAll[i1 * B_TOK + q1] = b;
    int j1 = atomicAdd(&cnt2[i1 * 2 + 1], 1);
    qlist2[(i1 * 2 + 1) * B_TOK + j1] = q1;
    wlist2[(i1 * 2 + 1) * B_TOK + j1] = p1;
  }
}

// Shared MFMA phase: read fragments of SB[bo..] and accumulate 16 MFMAs.
#define M_MFMA(bo)                                                          \
  do {                                                                      \
    sx8 af[4], bfr[4];                                                      \
    _Pragma("unroll")                                                       \
    for (int m_ = 0; m_ < 4; m_++)                                          \
      af[m_] = *(const sx8*)(&SB[(bo) + (wr * 64 + m_ * 16 + lrow) * LSTR + khalf * 8]); \
    _Pragma("unroll")                                                       \
    for (int n_ = 0; n_ < 4; n_++)                                          \
      bfr[n_] = *(const sx8*)(&SB[(bo) + (128 + wc * 64 + n_ * 16 + lrow) * LSTR + khalf * 8]); \
    _Pragma("unroll")                                                       \
    for (int m_ = 0; m_ < 4; m_++)                                          \
      _Pragma("unroll")                                                     \
      for (int n_ = 0; n_ < 4; n_++)                                        \
        acc[m_][n_] = __builtin_amdgcn_mfma_f32_16x16x32_bf16(af[m_], bfr[n_], acc[m_][n_], 0, 0, 0); \
  } while (0)

// GEMM1 split-K: partials[kc][slot][col] = x_gather . W1[e]^T over chunk kc.
// 128x128 tile, 4 waves, BK=32, reg-staged depth-2 vmcnt pipeline.
__global__ __launch_bounds__(256) void k_mlp1(
    const float* __restrict__ x, const float* __restrict__ W1,
    const int* __restrict__ cnt, const int* __restrict__ tokAll,
    float* __restrict__ partials, int CH)
{
  int e = blockIdx.z;
  int tt = blockIdx.y >> 2, nt = blockIdx.y & 3;
  int kc = blockIdx.x;

  __shared__ int sh_ne, sh_eoff;
  __shared__ __align__(16) short SB[2 * BUFS];
  __shared__ int toks[128];

  int t = threadIdx.x;
  if (t == 0) {
    int off = 0;
    for (int k = 0; k < e; k++) off += cnt[k];
    sh_eoff = off; sh_ne = cnt[e];
  }
  __syncthreads();
  int ne = sh_ne, eoff = sh_eoff, row0 = tt * 128;
  if (row0 >= ne) return;
  int nvalid = min(128, ne - row0);

  if (t < 128) toks[t] = tokAll[e * B_TOK + row0 + min(t, nvalid - 1)];
  __syncthreads();

  int r4 = t >> 2, kch = t & 3;  // thread stages rows r4 & r4+64 of A and B
  const float* xr0 = x + (size_t)toks[r4] * M_DIM;
  const float* xr1 = x + (size_t)toks[r4 + 64] * M_DIM;
  const float* wr0 = W1 + ((size_t)e * H_DIM + nt * 128 + r4) * M_DIM;
  const float* wr1 = W1 + ((size_t)e * H_DIM + nt * 128 + r4 + 64) * M_DIM;

  int lane = t & 63, wave = t >> 6;
  int wr = wave >> 1, wc = wave & 1;
  int lrow = lane & 15, khalf = lane >> 4;

  fx4 z4 = {0.f, 0.f, 0.f, 0.f};
  fx4 acc[4][4];
#pragma unroll
  for (int m = 0; m < 4; m++)
#pragma unroll
    for (int n = 0; n < 4; n++) acc[m][n] = z4;

  int s0 = kc * CH, s1 = min(s0 + CH, NSTEP);  // s1-s0 >= 33 always
  sx8 zv = {0, 0, 0, 0, 0, 0, 0, 0};

#define M1_LOAD(p, sN)                                                       \
  do {                                                                       \
    int off_ = (sN) * 32 + kch * 8;                                          \
    int oc_ = min(off_, M_DIM - 8);                                          \
    p##ok = (off_ + 8 <= M_DIM);                                             \
    p##A0 = *(const fx4*)(xr0 + oc_); p##A0b = *(const fx4*)(xr0 + oc_ + 4); \
    p##A1 = *(const fx4*)(xr1 + oc_); p##A1b = *(const fx4*)(xr1 + oc_ + 4); \
    p##B0 = *(const fx4*)(wr0 + oc_); p##B0b = *(const fx4*)(wr0 + oc_ + 4); \
    p##B1 = *(const fx4*)(wr1 + oc_); p##B1b = *(const fx4*)(wr1 + oc_ + 4); \
  } while (0)

#define M1_PACK(p, wo)                                                       \
  do {                                                                       \
    sx8 t0_ = p##ok ? pack8(p##A0, p##A0b) : zv;                             \
    sx8 t1_ = p##ok ? pack8(p##A1, p##A1b) : zv;                             \
    sx8 t2_ = p##ok ? pack8(p##B0, p##B0b) : zv;                             \
    sx8 t3_ = p##ok ? pack8(p##B1, p##B1b) : zv;                             \
    *(sx8*)(&SB[(wo) + r4 * LSTR + kch * 8]) = t0_;                          \
    *(sx8*)(&SB[(wo) + (r4 + 64) * LSTR + kch * 8]) = t1_;                   \
    *(sx8*)(&SB[(wo) + (128 + r4) * LSTR + kch * 8]) = t2_;                  \
    *(sx8*)(&SB[(wo) + (128 + r4 + 64) * LSTR + kch * 8]) = t3_;             \
  } while (0)

  fx4 pA0, pA0b, pA1, pA1b, pB0, pB0b, pB1, pB1b; bool pok;
  fx4 qA0, qA0b, qA1, qA1b, qB0, qB0b, qB1, qB1b; bool qok;

  // prologue: buf0 = step s0; P holds raw s0+1; Q holds raw s0+2
  M1_LOAD(p, s0);
  M1_PACK(p, 0);
  M1_LOAD(p, s0 + 1);
  M1_LOAD(q, s0 + 2);
  pipe_barrier();

  int c = 0, s = s0;
  while (s < s1) {
    M_MFMA(c * BUFS);                         // consume step s
    if (s + 1 < s1) M1_PACK(p, (c ^ 1) * BUFS);  // vmcnt waits P only; Q stays out
    if (s + 3 < s1) M1_LOAD(p, s + 3);
    pipe_barrier();
    c ^= 1; s++;
    if (s >= s1) break;
    M_MFMA(c * BUFS);
    if (s + 1 < s1) M1_PACK(q, (c ^ 1) * BUFS);
    if (s + 3 < s1) M1_LOAD(q, s + 3);
    pipe_barrier();
    c ^= 1; s++;
  }

#pragma unroll
  for (int m = 0; m < 4; m++)
#pragma unroll
    for (int n = 0; n < 4; n++) {
      int colg = nt * 128 + wc * 64 + n * 16 + lrow;
#pragma unroll
      for (int r = 0; r < 4; r++) {
        int rl = wr * 64 + m * 16 + khalf * 4 + r;
        if (rl < nvalid) {
          int grow = eoff + row0 + rl;
          partials[((size_t)kc * 2048 + grow) * H_DIM + colg] = acc[m][n][r];
        }
      }
    }
#undef M1_LOAD
#undef M1_PACK
}

// Reduce split-K partials + bias + relu -> bf16 hbuf.
__global__ __launch_bounds__(256) void k_hreduce(
    const float* __restrict__ partials, const float* __restrict__ b1,
    const int* __restrict__ cnt, short* __restrict__ hbuf, int KC)
{
  __shared__ int sc[E_NUM];
  int t = threadIdx.x;
  if (t < E_NUM) sc[t] = cnt[t];
  __syncthreads();
  int i = (blockIdx.x * 256 + t) * 4;
  int slot = i >> 9;
  int e = 0, off = 0;
  for (int k = 0; k < E_NUM - 1; k++) {
    if (slot >= off + sc[k]) { off += sc[k]; e++; } else break;
  }
  fx4 v = *(const fx4*)(partials + i);
  for (int kc = 1; kc < KC; kc++)
    v += *(const fx4*)(partials + (size_t)kc * 2048 * H_DIM + i);
  fx4 bv = *(const fx4*)(b1 + e * H_DIM + (i & (H_DIM - 1)));
  sx4 o;
#pragma unroll
  for (int j = 0; j < 4; j++) o[j] = f2bf(fmaxf(v[j] + bv[j], 0.f));
  *(sx4*)(hbuf + i) = o;
}

// GEMM2 pass (ord=0: overwrite, ord=1: accumulate). 128x128 tile, K=512,
// reg-staged depth-2 vmcnt pipeline.
__global__ __launch_bounds__(256) void k_mlp2(
    const short* __restrict__ hbuf, const float* __restrict__ W2,
    const float* __restrict__ b2, const int* __restrict__ cnt,
    const int* __restrict__ cnt2, const int* __restrict__ tokAll,
    const int* __restrict__ qlist2, const float* __restrict__ wlist2,
    float* __restrict__ out, int ord)
{
  int e = blockIdx.z, mt = blockIdx.y, tt = blockIdx.x;

  __shared__ int sh_ne2, sh_eoff;
  __shared__ __align__(16) short SB[2 * BUFS];
  __shared__ int sl[128];
  __shared__ int tok2[128];
  __shared__ float wts[128];

  int t = threadIdx.x;
  if (t == 0) {
    int off = 0;
    for (int k = 0; k < e; k++) off += cnt[k];
    sh_eoff = off; sh_ne2 = cnt2[e * 2 + ord];
  }
  __syncthreads();
  int ne2 = sh_ne2, eoff = sh_eoff, row0 = tt * 128;
  if (row0 >= ne2) return;
  int nvalid = min(128, ne2 - row0);

  if (t < 128) {
    int j = row0 + min(t, nvalid - 1);
    int q = qlist2[(e * 2 + ord) * B_TOK + j];
    sl[t] = eoff + q;
    tok2[t] = tokAll[e * B_TOK + q];
    wts[t] = (t < nvalid) ? wlist2[(e * 2 + ord) * B_TOK + j] : 0.f;
  }
  __syncthreads();

  int r4 = t >> 2, kch = t & 3;
  const short* hr0 = hbuf + (size_t)sl[r4] * H_DIM;
  const short* hr1 = hbuf + (size_t)sl[r4 + 64] * H_DIM;
  const float* w20 = W2 + ((size_t)e * M_DIM + min(mt * 128 + r4, M_DIM - 1)) * H_DIM;
  const float* w21 = W2 + ((size_t)e * M_DIM + min(mt * 128 + r4 + 64, M_DIM - 1)) * H_DIM;

  int lane = t & 63, wave = t >> 6;
  int wr = wave >> 1, wc = wave & 1;
  int lrow = lane & 15, khalf = lane >> 4;

  fx4 z4 = {0.f, 0.f, 0.f, 0.f};
  fx4 acc[4][4];
#pragma unroll
  for (int m = 0; m < 4; m++)
#pragma unroll
    for (int n = 0; n < 4; n++) acc[m][n] = z4;

#define M2_LOAD(p, sN)                                                       \
  do {                                                                       \
    int off_ = (sN) * 32 + kch * 8;                                          \
    p##As0 = *(const sx8*)(hr0 + off_);                                      \
    p##As1 = *(const sx8*)(hr1 + off_);                                      \
    p##B0 = *(const fx4*)(w20 + off_); p##B0b = *(const fx4*)(w20 + off_ + 4); \
    p##B1 = *(const fx4*)(w21 + off_); p##B1b = *(const fx4*)(w21 + off_ + 4); \
  } while (0)

#define M2_PACK(p, wo)                                                       \
  do {                                                                       \
    sx8 t2_ = pack8(p##B0, p##B0b);                                          \
    sx8 t3_ = pack8(p##B1, p##B1b);                                          \
    *(sx8*)(&SB[(wo) + r4 * LSTR + kch * 8]) = p##As0;                       \
    *(sx8*)(&SB[(wo) + (r4 + 64) * LSTR + kch * 8]) = p##As1;                \
    *(sx8*)(&SB[(wo) + (128 + r4) * LSTR + kch * 8]) = t2_;                  \
    *(sx8*)(&SB[(wo) + (128 + r4 + 64) * LSTR + kch * 8]) = t3_;             \
  } while (0)

  sx8 pAs0, pAs1; fx4 pB0, pB0b, pB1, pB1b;
  sx8 qAs0, qAs1; fx4 qB0, qB0b, qB1, qB1b;

  M2_LOAD(p, 0);
  M2_PACK(p, 0);
  M2_LOAD(p, 1);
  M2_LOAD(q, 2);
  pipe_barrier();

  int c = 0, s = 0;
  while (s < 16) {  // K = 512 = 16 * 32
    M_MFMA(c * BUFS);
    if (s + 1 < 16) M2_PACK(p, (c ^ 1) * BUFS);
    if (s + 3 < 16) M2_LOAD(p, s + 3);
    pipe_barrier();
    c ^= 1; s++;
    if (s >= 16) break;
    M_MFMA(c * BUFS);
    if (s + 1 < 16) M2_PACK(q, (c ^ 1) * BUFS);
    if (s + 3 < 16) M2_LOAD(q, s + 3);
    pipe_barrier();
    c ^= 1; s++;
  }

#pragma unroll
  for (int m = 0; m < 4; m++)
#pragma unroll
    for (int n = 0; n < 4; n++) {
      int colg = mt * 128 + wc * 64 + n * 16 + lrow;
      if (colg < M_DIM) {
        float b2v = b2[(size_t)e * M_DIM + colg];
#pragma unroll
        for (int r = 0; r < 4; r++) {
          int rl = wr * 64 + m * 16 + khalf * 4 + r;
          if (rl < nvalid) {
            float v = wts[rl] * (acc[m][n][r] + b2v);
            float* dst = out + (size_t)tok2[rl] * M_DIM + colg;
            if (ord == 0) *dst = v;
            else *dst += v;
          }
        }
      }
    }
#undef M2_LOAD
#undef M2_PACK
}

extern "C" void kernel_launch(void* const* d_in, const int* in_sizes, int n_in,
                              void* d_out, int out_size, void* d_ws, size_t ws_size,
                              hipStream_t stream) {
  const float* x  = (const float*)d_in[0];
  const float* W1 = (const float*)d_in[1];
  const float* b1 = (const float*)d_in[2];
  const float* W2 = (const float*)d_in[3];
  const float* b2 = (const float*)d_in[4];
  const float* Wr = (const float*)d_in[5];
  float* out = (float*)d_out;

  int KC = (ws_size >= (size_t)36 * 1024 * 1024) ? 8 : 4;
  int CH = (NSTEP + KC - 1) / KC;

  char* p = (char*)d_ws;
  float* partials = (float*)p;        p += (size_t)KC * 2048 * H_DIM * 4;
  short* hbuf     = (short*)p;        p += (size_t)2048 * H_DIM * 2;
  int*   cnt      = (int*)p;          p += 64;
  int*   cnt2     = (int*)p;          p += 64;
  int*   tokAll   = (int*)p;          p += E_NUM * B_TOK * 4;
  int*   qlist2   = (int*)p;          p += 2 * E_NUM * B_TOK * 4;
  float* wlist2   = (float*)p;

  k_zero<<<1, 64, 0, stream>>>(cnt, cnt2);
  k_router<<<B_TOK, 256, 0, stream>>>(x, Wr, cnt, cnt2, tokAll, qlist2, wlist2);
  k_mlp1<<<dim3(KC, 12, E_NUM), 256, 0, stream>>>(x, W1, cnt, tokAll, partials, CH);
  k_hreduce<<<1024, 256, 0, stream>>>(partials, b1, cnt, hbuf, KC);
  k_mlp2<<<dim3(2, 79, E_NUM), 256, 0, stream>>>(hbuf, W2, b2, cnt, cnt2, tokAll,
                                                 qlist2, wlist2, out, 0);
  k_mlp2<<<dim3(2, 79, E_NUM), 256, 0, stream>>>(hbuf, W2, b2, cnt, cnt2, tokAll,
                                                 qlist2, wlist2, out, 1);
}

// Round 7
// 376.589 us; speedup vs baseline: 1.1450x; 1.1450x over previous
//
#include <hip/hip_runtime.h>
#include <hip/hip_bf16.h>

// MoE top-2 of 8: B=1024 tokens, M=10000, H=512.
// R7: bf16 operands + global_load_lds + 3-buffer counted-vmcnt pipeline
// (T3/T4): per step issue stage s+2, s_waitcnt vmcnt(4), raw s_barrier with
// lgkm-only drain. No full vmcnt drain inside the K-loop.

#define B_TOK 1024
#define M_DIM 10000
#define E_NUM 8
#define H_DIM 512
#define NSTEP 313  // ceil(10000/32)

typedef __attribute__((ext_vector_type(4))) float fx4;
typedef __attribute__((ext_vector_type(8))) short sx8;
typedef __attribute__((ext_vector_type(4))) short sx4;

__device__ __forceinline__ short f2bf(float f) {
  union { __hip_bfloat16 h; short s; } u;
  u.h = __float2bfloat16(f);
  return u.s;
}

__device__ __forceinline__ sx8 pack8(fx4 a, fx4 b) {
  sx8 r;
  r[0] = f2bf(a[0]); r[1] = f2bf(a[1]); r[2] = f2bf(a[2]); r[3] = f2bf(a[3]);
  r[4] = f2bf(b[0]); r[5] = f2bf(b[1]); r[6] = f2bf(b[2]); r[7] = f2bf(b[3]);
  return r;
}

__device__ __forceinline__ void gload16(const short* g, short* l) {
  __builtin_amdgcn_global_load_lds(
      (const __attribute__((address_space(1))) void*)g,
      (__attribute__((address_space(3))) void*)l, 16, 0, 0);
}

// Pipeline phase boundary: drain LDS ops only, counted vmem, raw barrier.
#define PIPE_SYNC(VM)                                              \
  do {                                                             \
    asm volatile("s_waitcnt lgkmcnt(0)" ::: "memory");             \
    __builtin_amdgcn_sched_barrier(0);                             \
    asm volatile("s_waitcnt vmcnt(" #VM ")" ::: "memory");         \
    __builtin_amdgcn_sched_barrier(0);                             \
    __builtin_amdgcn_s_barrier();                                  \
    __builtin_amdgcn_sched_barrier(0);                             \
  } while (0)

__global__ void k_zero(int* cnt, int* cnt2, int* zpad) {
  if (threadIdx.x < E_NUM) cnt[threadIdx.x] = 0;
  if (threadIdx.x < 2 * E_NUM) cnt2[threadIdx.x] = 0;
  if (threadIdx.x < 16) zpad[threadIdx.x] = 0;
}

// f32 -> bf16 bulk convert.
__global__ __launch_bounds__(256) void k_cvt(
    const float* __restrict__ src, short* __restrict__ dst)
{
  size_t i = ((size_t)blockIdx.x * 256 + threadIdx.x) * 8;
  fx4 a = *(const fx4*)(src + i);
  fx4 b = *(const fx4*)(src + i + 4);
  *(sx8*)(dst + i) = pack8(a, b);
}

// Router: f64-accumulated logits (top-2 flip safety vs numpy ref), softmax,
// fused x -> bf16 conversion.
__global__ __launch_bounds__(256) void k_router(
    const float* __restrict__ x, const float* __restrict__ Wr,
    int* __restrict__ cnt, int* __restrict__ cnt2,
    int* __restrict__ tokAll, int* __restrict__ qlist2, float* __restrict__ wlist2,
    short* __restrict__ xb)
{
  int b = blockIdx.x, t = threadIdx.x;
  const float* xr = x + (size_t)b * M_DIM;
  short* xbr = xb + (size_t)b * M_DIM;
  double acc[E_NUM];
#pragma unroll
  for (int e = 0; e < E_NUM; e++) acc[e] = 0.0;
  for (int m = t; m < M_DIM; m += 256) {
    float xv = xr[m];
    xbr[m] = f2bf(xv);
#pragma unroll
    for (int e = 0; e < E_NUM; e++)
      acc[e] += (double)xv * (double)Wr[e * M_DIM + m];
  }
#pragma unroll
  for (int e = 0; e < E_NUM; e++) {
#pragma unroll
    for (int off = 32; off > 0; off >>= 1)
      acc[e] += __shfl_xor(acc[e], off);
  }
  __shared__ double part[4][E_NUM];
  int wave = t >> 6;
  if ((t & 63) == 0) {
    for (int e = 0; e < E_NUM; e++) part[wave][e] = acc[e];
  }
  __syncthreads();
  if (t == 0) {
    double lg[E_NUM];
    for (int e = 0; e < E_NUM; e++)
      lg[e] = part[0][e] + part[1][e] + part[2][e] + part[3][e];
    int i0 = 0;
    for (int e = 1; e < E_NUM; e++) if (lg[e] > lg[i0]) i0 = e;
    int i1 = (i0 == 0) ? 1 : 0;
    for (int e = 0; e < E_NUM; e++) if (e != i0 && lg[e] > lg[i1]) i1 = e;
    double ex = exp(lg[i1] - lg[i0]);
    float p0 = (float)(1.0 / (1.0 + ex));
    float p1 = (float)(ex / (1.0 + ex));
    int q0 = atomicAdd(&cnt[i0], 1);
    tokAll[i0 * B_TOK + q0] = b;
    int j0 = atomicAdd(&cnt2[i0 * 2 + 0], 1);
    qlist2[(i0 * 2 + 0) * B_TOK + j0] = q0;
    wlist2[(i0 * 2 + 0) * B_TOK + j0] = p0;
    int q1 = atomicAdd(&cnt[i1], 1);
    tokAll[i1 * B_TOK + q1] = b;
    int j1 = atomicAdd(&cnt2[i1 * 2 + 1], 1);
    qlist2[(i1 * 2 + 1) * B_TOK + j1] = q1;
    wlist2[(i1 * 2 + 1) * B_TOK + j1] = p1;
  }
}

// Fragment reads + 16 MFMAs from 3-buffer LDS.
#define M_MFMA3(cb)                                                         \
  do {                                                                      \
    sx8 af[4], bfr[4];                                                      \
    _Pragma("unroll")                                                       \
    for (int m_ = 0; m_ < 4; m_++)                                          \
      af[m_] = *(const sx8*)(LA[cb] + (wr * 64 + m_ * 16 + lrow) * 32 + khalf * 8); \
    _Pragma("unroll")                                                       \
    for (int n_ = 0; n_ < 4; n_++)                                          \
      bfr[n_] = *(const sx8*)(LB[cb] + (wc * 64 + n_ * 16 + lrow) * 32 + khalf * 8); \
    __builtin_amdgcn_s_setprio(1);                                          \
    _Pragma("unroll")                                                       \
    for (int m_ = 0; m_ < 4; m_++)                                          \
      _Pragma("unroll")                                                     \
      for (int n_ = 0; n_ < 4; n_++)                                        \
        acc[m_][n_] = __builtin_amdgcn_mfma_f32_16x16x32_bf16(af[m_], bfr[n_], acc[m_][n_], 0, 0, 0); \
    __builtin_amdgcn_s_setprio(0);                                          \
  } while (0)

// GEMM1 split-K: partials[kc][slot][col] = xb_gather . W1b[e]^T over chunk kc.
// 128x128 tile, 4 waves, BK=32, 3-buffer gload_lds pipeline.
__global__ __launch_bounds__(256) void k_mlp1g(
    const short* __restrict__ xb, const short* __restrict__ Wb,
    const int* __restrict__ cnt, const int* __restrict__ tokAll,
    float* __restrict__ partials, const short* __restrict__ zpad, int CH)
{
  int e = blockIdx.z;
  int tt = blockIdx.y >> 2, nt = blockIdx.y & 3;
  int kc = blockIdx.x;

  __shared__ int sh_ne, sh_eoff;
  __shared__ __align__(16) short LA[3][4096];  // [buf][128 rows][32 cols]
  __shared__ __align__(16) short LB[3][4096];
  __shared__ int toks[128];

  int t = threadIdx.x;
  if (t == 0) {
    int off = 0;
    for (int k = 0; k < e; k++) off += cnt[k];
    sh_eoff = off; sh_ne = cnt[e];
  }
  __syncthreads();
  int ne = sh_ne, eoff = sh_eoff, row0 = tt * 128;
  if (row0 >= ne) return;
  int nvalid = min(128, ne - row0);
  if (t < 128) toks[t] = tokAll[e * B_TOK + row0 + min(t, nvalid - 1)];
  __syncthreads();

  int lane = t & 63, wave = t >> 6;
  int srow = wave * 32 + (lane >> 2);   // staged row within tile
  int scol = (lane & 3) * 8;            // staged k-chunk (8 bf16)
  const short* ap0 = xb + (size_t)toks[srow] * M_DIM + scol;
  const short* ap1 = xb + (size_t)toks[srow + 16] * M_DIM + scol;
  const short* bp0 = Wb + ((size_t)e * H_DIM + nt * 128 + srow) * M_DIM + scol;
  const short* bp1 = bp0 + (size_t)16 * M_DIM;
  int ld0 = (wave * 32) * 32;  // wave-uniform LDS base; lane dest = base + lane*16B
  int ld1 = (wave * 32 + 16) * 32;

  int wr = wave >> 1, wc = wave & 1;
  int lrow = lane & 15, khalf = lane >> 4;

  fx4 z4 = {0.f, 0.f, 0.f, 0.f};
  fx4 acc[4][4];
#pragma unroll
  for (int m = 0; m < 4; m++)
#pragma unroll
    for (int n = 0; n < 4; n++) acc[m][n] = z4;

  int s0 = kc * CH, s1 = min(s0 + CH, NSTEP);
  int S = s1 - s0;  // >= 33

#define STAGE1(buf, sN)                                        \
  do {                                                         \
    int ko_ = (sN) * 32;                                       \
    bool ok_ = (ko_ + scol + 8 <= M_DIM);                      \
    gload16(ok_ ? (ap0 + ko_) : zpad, LA[buf] + ld0);          \
    gload16(ok_ ? (ap1 + ko_) : zpad, LA[buf] + ld1);          \
    gload16(ok_ ? (bp0 + ko_) : zpad, LB[buf] + ld0);          \
    gload16(ok_ ? (bp1 + ko_) : zpad, LB[buf] + ld1);          \
  } while (0)

  STAGE1(0, s0);
  STAGE1(1, s0 + 1);

  for (int i = 0; i < S; i++) {
    if (i + 1 < S) PIPE_SYNC(4);   // step-i loads landed; step-i+1 stays in flight
    else PIPE_SYNC(0);
    int cb = i % 3;
    if (i + 2 < S) STAGE1((i + 2) % 3, s0 + i + 2);
    M_MFMA3(cb);
  }

#pragma unroll
  for (int m = 0; m < 4; m++)
#pragma unroll
    for (int n = 0; n < 4; n++) {
      int colg = nt * 128 + wc * 64 + n * 16 + lrow;
#pragma unroll
      for (int r = 0; r < 4; r++) {
        int rl = wr * 64 + m * 16 + khalf * 4 + r;
        if (rl < nvalid) {
          int grow = eoff + row0 + rl;
          partials[((size_t)kc * 2048 + grow) * H_DIM + colg] = acc[m][n][r];
        }
      }
    }
#undef STAGE1
}

// Reduce split-K partials + bias + relu -> bf16 hbuf.
__global__ __launch_bounds__(256) void k_hreduce(
    const float* __restrict__ partials, const float* __restrict__ b1,
    const int* __restrict__ cnt, short* __restrict__ hbuf, int KC)
{
  __shared__ int sc[E_NUM];
  int t = threadIdx.x;
  if (t < E_NUM) sc[t] = cnt[t];
  __syncthreads();
  int i = (blockIdx.x * 256 + t) * 4;
  int slot = i >> 9;
  int e = 0, off = 0;
  for (int k = 0; k < E_NUM - 1; k++) {
    if (slot >= off + sc[k]) { off += sc[k]; e++; } else break;
  }
  fx4 v = *(const fx4*)(partials + i);
  for (int kc = 1; kc < KC; kc++)
    v += *(const fx4*)(partials + (size_t)kc * 2048 * H_DIM + i);
  fx4 bv = *(const fx4*)(b1 + e * H_DIM + (i & (H_DIM - 1)));
  sx4 o;
#pragma unroll
  for (int j = 0; j < 4; j++) o[j] = f2bf(fmaxf(v[j] + bv[j], 0.f));
  *(sx4*)(hbuf + i) = o;
}

// GEMM2 pass (ord=0 overwrite, ord=1 accumulate). 128x128 tile, K=512,
// 3-buffer gload_lds pipeline (16 steps, no tail).
__global__ __launch_bounds__(256) void k_mlp2g(
    const short* __restrict__ hbuf, const short* __restrict__ Wb,
    const float* __restrict__ b2, const int* __restrict__ cnt,
    const int* __restrict__ cnt2, const int* __restrict__ tokAll,
    const int* __restrict__ qlist2, const float* __restrict__ wlist2,
    float* __restrict__ out, int ord)
{
  int e = blockIdx.z, mt = blockIdx.y, tt = blockIdx.x;

  __shared__ int sh_ne2, sh_eoff;
  __shared__ __align__(16) short LA[3][4096];
  __shared__ __align__(16) short LB[3][4096];
  __shared__ int sl[128];
  __shared__ int tok2[128];
  __shared__ float wts[128];

  int t = threadIdx.x;
  if (t == 0) {
    int off = 0;
    for (int k = 0; k < e; k++) off += cnt[k];
    sh_eoff = off; sh_ne2 = cnt2[e * 2 + ord];
  }
  __syncthreads();
  int ne2 = sh_ne2, eoff = sh_eoff, row0 = tt * 128;
  if (row0 >= ne2) return;
  int nvalid = min(128, ne2 - row0);

  if (t < 128) {
    int j = row0 + min(t, nvalid - 1);
    int q = qlist2[(e * 2 + ord) * B_TOK + j];
    sl[t] = eoff + q;
    tok2[t] = tokAll[e * B_TOK + q];
    wts[t] = (t < nvalid) ? wlist2[(e * 2 + ord) * B_TOK + j] : 0.f;
  }
  __syncthreads();

  int lane = t & 63, wave = t >> 6;
  int srow = wave * 32 + (lane >> 2);
  int scol = (lane & 3) * 8;
  const short* ap0 = hbuf + (size_t)sl[srow] * H_DIM + scol;
  const short* ap1 = hbuf + (size_t)sl[srow + 16] * H_DIM + scol;
  const short* bp0 = Wb + ((size_t)e * M_DIM + min(mt * 128 + srow, M_DIM - 1)) * H_DIM + scol;
  const short* bp1 = Wb + ((size_t)e * M_DIM + min(mt * 128 + srow + 16, M_DIM - 1)) * H_DIM + scol;
  int ld0 = (wave * 32) * 32;
  int ld1 = (wave * 32 + 16) * 32;

  int wr = wave >> 1, wc = wave & 1;
  int lrow = lane & 15, khalf = lane >> 4;

  fx4 z4 = {0.f, 0.f, 0.f, 0.f};
  fx4 acc[4][4];
#pragma unroll
  for (int m = 0; m < 4; m++)
#pragma unroll
    for (int n = 0; n < 4; n++) acc[m][n] = z4;

#define STAGE2(buf, sN)                          \
  do {                                           \
    int ko_ = (sN) * 32;                         \
    gload16(ap0 + ko_, LA[buf] + ld0);           \
    gload16(ap1 + ko_, LA[buf] + ld1);           \
    gload16(bp0 + ko_, LB[buf] + ld0);           \
    gload16(bp1 + ko_, LB[buf] + ld1);           \
  } while (0)

  STAGE2(0, 0);
  STAGE2(1, 1);

  for (int i = 0; i < 16; i++) {
    if (i + 1 < 16) PIPE_SYNC(4);
    else PIPE_SYNC(0);
    int cb = i % 3;
    if (i + 2 < 16) STAGE2((i + 2) % 3, i + 2);
    M_MFMA3(cb);
  }

#pragma unroll
  for (int m = 0; m < 4; m++)
#pragma unroll
    for (int n = 0; n < 4; n++) {
      int colg = mt * 128 + wc * 64 + n * 16 + lrow;
      if (colg < M_DIM) {
        float b2v = b2[(size_t)e * M_DIM + colg];
#pragma unroll
        for (int r = 0; r < 4; r++) {
          int rl = wr * 64 + m * 16 + khalf * 4 + r;
          if (rl < nvalid) {
            float v = wts[rl] * (acc[m][n][r] + b2v);
            float* dst = out + (size_t)tok2[rl] * M_DIM + colg;
            if (ord == 0) *dst = v;
            else *dst += v;
          }
        }
      }
    }
#undef STAGE2
}

extern "C" void kernel_launch(void* const* d_in, const int* in_sizes, int n_in,
                              void* d_out, int out_size, void* d_ws, size_t ws_size,
                              hipStream_t stream) {
  const float* x  = (const float*)d_in[0];
  const float* W1 = (const float*)d_in[1];
  const float* b1 = (const float*)d_in[2];
  const float* W2 = (const float*)d_in[3];
  const float* b2 = (const float*)d_in[4];
  const float* Wr = (const float*)d_in[5];
  float* out = (float*)d_out;

  const int KC = 8, CH = (NSTEP + KC - 1) / KC;  // 40

  char* p = (char*)d_ws;
  float* partials = (float*)p;        p += (size_t)KC * 2048 * H_DIM * 4;  // 33.5 MB
  short* hbuf     = (short*)p;        p += (size_t)2048 * H_DIM * 2;       // 2 MB
  int*   cnt      = (int*)p;          p += 64;
  int*   cnt2     = (int*)p;          p += 64;
  int*   tokAll   = (int*)p;          p += E_NUM * B_TOK * 4;
  int*   qlist2   = (int*)p;          p += 2 * E_NUM * B_TOK * 4;
  float* wlist2   = (float*)p;        p += 2 * E_NUM * B_TOK * 4;
  int*   zpad     = (int*)p;          p += 64;
  short* xb       = (short*)p;        p += (size_t)B_TOK * M_DIM * 2;      // 20.5 MB
  short* Wb       = (short*)p;                                             // 82 MB

  k_zero<<<1, 64, 0, stream>>>(cnt, cnt2, zpad);
  k_router<<<B_TOK, 256, 0, stream>>>(x, Wr, cnt, cnt2, tokAll, qlist2, wlist2, xb);
  k_cvt<<<20000, 256, 0, stream>>>(W1, Wb);
  k_mlp1g<<<dim3(KC, 12, E_NUM), 256, 0, stream>>>(xb, Wb, cnt, tokAll, partials,
                                                   (const short*)zpad, CH);
  k_hreduce<<<1024, 256, 0, stream>>>(partials, b1, cnt, hbuf, KC);
  k_cvt<<<20000, 256, 0, stream>>>(W2, Wb);
  k_mlp2g<<<dim3(2, 79, E_NUM), 256, 0, stream>>>(hbuf, Wb, b2, cnt, cnt2, tokAll,
                                                  qlist2, wlist2, out, 0);
  k_mlp2g<<<dim3(2, 79, E_NUM), 256, 0, stream>>>(hbuf, Wb, b2, cnt, cnt2, tokAll,
                                                  qlist2, wlist2, out, 1);
}